// Round 1
// baseline (260.436 us; speedup 1.0000x reference)
//
#include <hip/hip_runtime.h>
#include <math.h>

#define NB 4096
#define NV 778
#define NJ 16
#define NC 30
#define NS 10
#define NF 1538
#define VC3 (NV*3)          // 2334
#define JVROW (799*3)       // 2397 floats per batch in jv

// output float offsets
#define OUT_JV    0
#define OUT_FACES (NB*799*3)                 // 9,818,112
#define OUT_POSES (OUT_FACES + NB*NF*3)      // 28,717,056

// ws float offsets
#define WS_JT   0          // 48
#define WS_JS   48         // 480
#define WS_PD   528        // 135*2334 = 315090
#define WS_PW   315620     // NB*135 = 552960
#define WS_AR   868580     // NB*192 = 786432
// total = 1,655,012 floats = 6.62 MB

__device__ const int d_pos16[16] = {0,1,2,3,5,6,7,9,10,11,13,14,15,17,18,19};

// ---------------- kernel 1: batch-independent constants ----------------
__global__ __launch_bounds__(256) void k_consts(const float* __restrict__ jr,
                                                const float* __restrict__ vt,
                                                const float* __restrict__ sd,
                                                float* __restrict__ ws)
{
    int w = (blockIdx.x * blockDim.x + threadIdx.x) >> 6;
    int lane = threadIdx.x & 63;
    if (w >= 528) return;
    float acc = 0.f;
    if (w < 48) {
        int j = w / 3, c = w % 3;
        for (int v = lane; v < NV; v += 64) acc += jr[j*NV + v] * vt[v*3 + c];
    } else {
        int q = w - 48;                  // q = (j*3+c)*10 + s
        int j = q / 30, rem = q % 30, c = rem / 10, s = rem % 10;
        for (int v = lane; v < NV; v += 64) acc += jr[j*NV + v] * sd[v*30 + c*10 + s];
    }
    for (int off = 32; off; off >>= 1) acc += __shfl_down(acc, off);
    if (lane == 0) ws[w] = acc;          // JT at 0, JS at 48 contiguous
}

// ---------------- kernel 2: transpose posedirs -> PD[135][2334] ----------------
__global__ __launch_bounds__(256) void k_transpose(const float* __restrict__ pdin,
                                                   float* __restrict__ pd)
{
    __shared__ float tile[32][33];
    int q0 = blockIdx.x * 32, p0 = blockIdx.y * 32;
    int tx = threadIdx.x, ty = threadIdx.y;          // block (32,8)
    #pragma unroll
    for (int i = 0; i < 4; i++) {
        int q = q0 + ty + i*8, p = p0 + tx;
        if (q < VC3 && p < 135) tile[ty + i*8][tx] = pdin[q*135 + p];
    }
    __syncthreads();
    #pragma unroll
    for (int i = 0; i < 4; i++) {
        int p = p0 + ty + i*8, q = q0 + tx;
        if (p < 135 && q < VC3) pd[p*VC3 + q] = tile[tx][ty + i*8];
    }
}

// ---------------- kernel 3: per-batch pose/FK ----------------
__global__ __launch_bounds__(64) void k_batch(const float* __restrict__ rot,
                                              const float* __restrict__ pp,
                                              const float* __restrict__ sp,
                                              const float* __restrict__ hc,
                                              const float* __restrict__ hm,
                                              const float* __restrict__ ws,
                                              float* __restrict__ out)
{
    __shared__ float poses_s[48];
    __shared__ float R_s[16][9];
    __shared__ float Jp_s[48];
    __shared__ float A_s[16][12];
    float* pw_ws = (float*)ws + WS_PW;   // cast away const for ws writes
    float* ar_ws = (float*)ws + WS_AR;

    int b = blockIdx.x, t = threadIdx.x;

    if (t < 3) poses_s[t] = rot[b*3 + t];
    if (t < 45) {
        float a = hm[t];
        for (int s = 0; s < NC; s++) a += pp[b*NC + s] * hc[s*45 + t];
        poses_s[3 + t] = a;
    }
    __syncthreads();
    if (t < 48) out[OUT_POSES + (size_t)b*48 + t] = poses_s[t];

    if (t < 48) {
        float a = ws[WS_JT + t];
        const float* js = ws + WS_JS + t*10;
        float acc = a;
        for (int s = 0; s < NS; s++) acc += js[s] * sp[b*NS + s];
        Jp_s[t] = acc;
    }
    if (t < 16) {
        float x = poses_s[t*3], y = poses_s[t*3+1], z = poses_s[t*3+2];
        float th = sqrtf(x*x + y*y + z*z + 1e-8f);
        float kx = x/th, ky = y/th, kz = z/th;
        float s = sinf(th), c = cosf(th), oc = 1.f - c;
        float* R = R_s[t];
        R[0] = 1.f + oc*(-(ky*ky + kz*kz));
        R[1] = -s*kz + oc*(kx*ky);
        R[2] =  s*ky + oc*(kx*kz);
        R[3] =  s*kz + oc*(kx*ky);
        R[4] = 1.f + oc*(-(kx*kx + kz*kz));
        R[5] = -s*kx + oc*(ky*kz);
        R[6] = -s*ky + oc*(kx*kz);
        R[7] =  s*kx + oc*(ky*kz);
        R[8] = 1.f + oc*(-(kx*kx + ky*ky));
    }
    __syncthreads();

    // pose blendshape coefficients pw = (R[1:] - I)
    for (int i = t; i < 135; i += 64) {
        int j = 1 + i/9, e = i % 9;
        float v = R_s[j][e] - ((e == 0 || e == 4 || e == 8) ? 1.f : 0.f);
        pw_ws[(size_t)b*135 + i] = v;
    }

    // forward kinematics (12 lanes compute the 3x4 affine rows)
    if (t < 12) {
        int r = t >> 2, c = t & 3;
        A_s[0][t] = (c < 3) ? R_s[0][r*3 + c] : Jp_s[r];
    }
    __syncthreads();
    const int par[16] = {0,0,1,2,0,4,5,0,7,8,0,10,11,0,13,14};
    #pragma unroll
    for (int i = 1; i < 16; i++) {
        int p = par[i];
        if (t < 12) {
            int r = t >> 2, c = t & 3;
            float val;
            if (c < 3) {
                val = A_s[p][r*4+0]*R_s[i][0*3+c]
                    + A_s[p][r*4+1]*R_s[i][1*3+c]
                    + A_s[p][r*4+2]*R_s[i][2*3+c];
            } else {
                float t0 = Jp_s[i*3+0] - Jp_s[p*3+0];
                float t1 = Jp_s[i*3+1] - Jp_s[p*3+1];
                float t2 = Jp_s[i*3+2] - Jp_s[p*3+2];
                val = A_s[p][r*4+0]*t0 + A_s[p][r*4+1]*t1
                    + A_s[p][r*4+2]*t2 + A_s[p][r*4+3];
            }
            A_s[i][t] = val;
        }
        __syncthreads();
    }

    // FK joint positions into jv (positions per insert order)
    if (t < 48) {
        int j = t / 3, r = t % 3;
        out[OUT_JV + (size_t)b*JVROW + d_pos16[j]*3 + r] = A_s[j][r*4 + 3];
    }
    // A_rel = A_global with col3 -= Arot @ Jp
    for (int i = t; i < 192; i += 64) {
        int j = i / 12, rc = i % 12, r = rc >> 2, c = rc & 3;
        float val = A_s[j][r*4 + c];
        if (c == 3) {
            val -= A_s[j][r*4+0]*Jp_s[j*3+0]
                 + A_s[j][r*4+1]*Jp_s[j*3+1]
                 + A_s[j][r*4+2]*Jp_s[j*3+2];
        }
        ar_ws[(size_t)b*192 + i] = val;
    }
}

// ---------------- kernel 4: per-vertex blendshapes + LBS ----------------
__global__ __launch_bounds__(256) void k_verts(const float* __restrict__ vt,
                                               const float* __restrict__ sd,
                                               const float* __restrict__ wts,
                                               const float* __restrict__ sp,
                                               const float* __restrict__ ws,
                                               float* __restrict__ out)
{
    const float* pd = ws + WS_PD;
    const float* pw = ws + WS_PW;
    const float* ar = ws + WS_AR;

    int v = blockIdx.x * 64 + (threadIdx.x & 63);
    int wl = threadIdx.x >> 6;
    int b0 = blockIdx.y * 32 + wl * 8;
    if (v >= NV) return;

    float w16[16];
    #pragma unroll
    for (int j = 0; j < 16; j++) w16[j] = wts[v*16 + j];
    float vt3[3] = { vt[v*3], vt[v*3+1], vt[v*3+2] };
    float sd30[30];
    #pragma unroll
    for (int i = 0; i < 30; i++) sd30[i] = sd[v*30 + i];

    float acc[8][3];
    #pragma unroll
    for (int bb = 0; bb < 8; bb++) {
        const float* spb = sp + (b0 + bb) * 10;
        #pragma unroll
        for (int c = 0; c < 3; c++) {
            float a = vt3[c];
            #pragma unroll
            for (int s = 0; s < 10; s++) a += spb[s] * sd30[c*10 + s];
            acc[bb][c] = a;
        }
    }

    const float* pdv = pd + v*3;
    const float* pwb = pw + (size_t)b0 * 135;
    #pragma unroll 3
    for (int p = 0; p < 135; p++) {
        float d0 = pdv[p*VC3 + 0];
        float d1 = pdv[p*VC3 + 1];
        float d2 = pdv[p*VC3 + 2];
        #pragma unroll
        for (int bb = 0; bb < 8; bb++) {
            float f = pwb[bb*135 + p];
            acc[bb][0] += f*d0; acc[bb][1] += f*d1; acc[bb][2] += f*d2;
        }
    }

    #pragma unroll
    for (int bb = 0; bb < 8; bb++) {
        int b = b0 + bb;
        const float* arb = ar + (size_t)b * 192;
        float x = acc[bb][0], y = acc[bb][1], z = acc[bb][2];
        float o0 = 0.f, o1 = 0.f, o2 = 0.f;
        #pragma unroll
        for (int j = 0; j < 16; j++) {
            float wj = w16[j];
            const float* m = arb + j*12;
            o0 += wj * (m[0]*x + m[1]*y + m[2]*z  + m[3]);
            o1 += wj * (m[4]*x + m[5]*y + m[6]*z  + m[7]);
            o2 += wj * (m[8]*x + m[9]*y + m[10]*z + m[11]);
        }
        size_t base = OUT_JV + (size_t)b*JVROW + (size_t)(21 + v)*3;
        out[base + 0] = o0; out[base + 1] = o1; out[base + 2] = o2;
        int fp = (v == 320) ? 4 : (v == 443) ? 8 : (v == 672) ? 12
               : (v == 555) ? 16 : (v == 744) ? 20 : -1;
        if (fp >= 0) {
            size_t jb = OUT_JV + (size_t)b*JVROW + (size_t)fp*3;
            out[jb + 0] = o0; out[jb + 1] = o1; out[jb + 2] = o2;
        }
    }
}

// ---------------- kernel 5: faces broadcast (as f32) ----------------
__global__ __launch_bounds__(256) void k_faces(const int* __restrict__ faces,
                                               float* __restrict__ out)
{
    int b = blockIdx.x;
    float* o = out + OUT_FACES + (size_t)b * (NF*3);
    for (int t = threadIdx.x; t < NF*3; t += 256) o[t] = (float)faces[t];
}

extern "C" void kernel_launch(void* const* d_in, const int* in_sizes, int n_in,
                              void* d_out, int out_size, void* d_ws, size_t ws_size,
                              hipStream_t stream)
{
    const float* rot  = (const float*)d_in[0];
    const float* pp   = (const float*)d_in[1];
    const float* sp   = (const float*)d_in[2];
    const float* vt   = (const float*)d_in[3];
    const float* sd   = (const float*)d_in[4];
    const float* pdir = (const float*)d_in[5];
    const float* jr   = (const float*)d_in[6];
    const float* wts  = (const float*)d_in[7];
    const float* hc   = (const float*)d_in[8];
    const float* hm   = (const float*)d_in[9];
    const int*   faces= (const int*)d_in[10];
    float* out = (float*)d_out;
    float* ws  = (float*)d_ws;

    k_consts<<<132, 256, 0, stream>>>(jr, vt, sd, ws);
    k_transpose<<<dim3((VC3+31)/32, (135+31)/32), dim3(32,8), 0, stream>>>(pdir, ws + WS_PD);
    k_batch<<<NB, 64, 0, stream>>>(rot, pp, sp, hc, hm, ws, out);
    k_verts<<<dim3((NV+63)/64, NB/32), 256, 0, stream>>>(vt, sd, wts, sp, ws, out);
    k_faces<<<NB, 256, 0, stream>>>(faces, out);
}

// Round 2
// 164.443 us; speedup vs baseline: 1.5837x; 1.5837x over previous
//
#include <hip/hip_runtime.h>
#include <math.h>

#define NB 4096
#define NV 778
#define NJ 16
#define NC 30
#define NS 10
#define NF 1538
#define VC3 (NV*3)          // 2334
#define JVROW (799*3)       // 2397 floats per batch in jv
#define PDP 784             // padded vertex stride for transposed posedirs
#define PD_PLANE (135*PDP)  // 105840

// output float offsets
#define OUT_JV    0
#define OUT_FACES (NB*799*3)                 // 9,818,112
#define OUT_POSES (OUT_FACES + NB*NF*3)      // 28,717,056

// ws float offsets
#define WS_JT   0                            // 48
#define WS_JS   48                           // 480
#define WS_PD   528                          // 3*135*784 = 317520
#define WS_PW   318048                       // NB*135 = 552960
#define WS_AR   871008                       // NB*192 = 786432
// end = 1,657,440 floats = 6.63 MB

__device__ const int d_pos16[16] = {0,1,2,3,5,6,7,9,10,11,13,14,15,17,18,19};

// ---------------- kernel 1: batch-independent constants ----------------
__global__ __launch_bounds__(256) void k_consts(const float* __restrict__ jr,
                                                const float* __restrict__ vt,
                                                const float* __restrict__ sd,
                                                float* __restrict__ ws)
{
    int w = (blockIdx.x * blockDim.x + threadIdx.x) >> 6;
    int lane = threadIdx.x & 63;
    if (w >= 528) return;
    float acc = 0.f;
    if (w < 48) {
        int j = w / 3, c = w % 3;
        for (int v = lane; v < NV; v += 64) acc += jr[j*NV + v] * vt[v*3 + c];
    } else {
        int q = w - 48;                  // q = (j*3+c)*10 + s
        int j = q / 30, rem = q % 30, c = rem / 10, s = rem % 10;
        for (int v = lane; v < NV; v += 64) acc += jr[j*NV + v] * sd[v*30 + c*10 + s];
    }
    for (int off = 32; off; off >>= 1) acc += __shfl_down(acc, off);
    if (lane == 0) ws[w] = acc;          // JT at 0, JS at 48 contiguous
}

// ---------------- kernel 2: transpose posedirs [V*3][135] -> [3][135][784] ----------------
__global__ __launch_bounds__(256) void k_transpose(const float* __restrict__ pdin,
                                                   float* __restrict__ pd)
{
    __shared__ float tile[96][136];      // 96 q-rows (32 verts * 3 c) x 135 p
    int v0 = blockIdx.x * 32;
    int q0 = v0 * 3;
    // coalesced read: pdin[q0*135 + idx]
    for (int idx = threadIdx.x; idx < 96*135; idx += 256) {
        int q = q0 + idx / 135;
        tile[idx / 135][idx % 135] = (q < VC3) ? pdin[(size_t)q0*135 + idx] : 0.f;
    }
    __syncthreads();
    // coalesced-ish write over v
    for (int wi = threadIdx.x; wi < 405*32; wi += 256) {
        int cp = wi >> 5, vi = wi & 31;
        int p = cp % 135, c = cp / 135;
        int v = v0 + vi;
        if (v < PDP) pd[(size_t)c*PD_PLANE + p*PDP + v] = tile[vi*3 + c][p];
    }
}

// ---------------- kernel 3: per-batch pose/FK ----------------
__global__ __launch_bounds__(64) void k_batch(const float* __restrict__ rot,
                                              const float* __restrict__ pp,
                                              const float* __restrict__ sp,
                                              const float* __restrict__ hc,
                                              const float* __restrict__ hm,
                                              const float* __restrict__ ws,
                                              float* __restrict__ out)
{
    __shared__ float poses_s[48];
    __shared__ float R_s[16][9];
    __shared__ float Jp_s[48];
    __shared__ float A_s[16][12];
    float* pw_ws = (float*)ws + WS_PW;
    float* ar_ws = (float*)ws + WS_AR;

    int b = blockIdx.x, t = threadIdx.x;

    if (t < 3) poses_s[t] = rot[b*3 + t];
    if (t < 45) {
        float a = hm[t];
        for (int s = 0; s < NC; s++) a += pp[b*NC + s] * hc[s*45 + t];
        poses_s[3 + t] = a;
    }
    __syncthreads();
    if (t < 48) out[OUT_POSES + (size_t)b*48 + t] = poses_s[t];

    if (t < 48) {
        float a = ws[WS_JT + t];
        const float* js = ws + WS_JS + t*10;
        float acc = a;
        for (int s = 0; s < NS; s++) acc += js[s] * sp[b*NS + s];
        Jp_s[t] = acc;
    }
    if (t < 16) {
        float x = poses_s[t*3], y = poses_s[t*3+1], z = poses_s[t*3+2];
        float th = sqrtf(x*x + y*y + z*z + 1e-8f);
        float kx = x/th, ky = y/th, kz = z/th;
        float s = sinf(th), c = cosf(th), oc = 1.f - c;
        float* R = R_s[t];
        R[0] = 1.f + oc*(-(ky*ky + kz*kz));
        R[1] = -s*kz + oc*(kx*ky);
        R[2] =  s*ky + oc*(kx*kz);
        R[3] =  s*kz + oc*(kx*ky);
        R[4] = 1.f + oc*(-(kx*kx + kz*kz));
        R[5] = -s*kx + oc*(ky*kz);
        R[6] = -s*ky + oc*(kx*kz);
        R[7] =  s*kx + oc*(ky*kz);
        R[8] = 1.f + oc*(-(kx*kx + ky*ky));
    }
    __syncthreads();

    for (int i = t; i < 135; i += 64) {
        int j = 1 + i/9, e = i % 9;
        float v = R_s[j][e] - ((e == 0 || e == 4 || e == 8) ? 1.f : 0.f);
        pw_ws[(size_t)b*135 + i] = v;
    }

    if (t < 12) {
        int r = t >> 2, c = t & 3;
        A_s[0][t] = (c < 3) ? R_s[0][r*3 + c] : Jp_s[r];
    }
    __syncthreads();
    const int par[16] = {0,0,1,2,0,4,5,0,7,8,0,10,11,0,13,14};
    #pragma unroll
    for (int i = 1; i < 16; i++) {
        int p = par[i];
        if (t < 12) {
            int r = t >> 2, c = t & 3;
            float val;
            if (c < 3) {
                val = A_s[p][r*4+0]*R_s[i][0*3+c]
                    + A_s[p][r*4+1]*R_s[i][1*3+c]
                    + A_s[p][r*4+2]*R_s[i][2*3+c];
            } else {
                float t0 = Jp_s[i*3+0] - Jp_s[p*3+0];
                float t1 = Jp_s[i*3+1] - Jp_s[p*3+1];
                float t2 = Jp_s[i*3+2] - Jp_s[p*3+2];
                val = A_s[p][r*4+0]*t0 + A_s[p][r*4+1]*t1
                    + A_s[p][r*4+2]*t2 + A_s[p][r*4+3];
            }
            A_s[i][t] = val;
        }
        __syncthreads();
    }

    if (t < 48) {
        int j = t / 3, r = t % 3;
        out[OUT_JV + (size_t)b*JVROW + d_pos16[j]*3 + r] = A_s[j][r*4 + 3];
    }
    for (int i = t; i < 192; i += 64) {
        int j = i / 12, rc = i % 12, r = rc >> 2, c = rc & 3;
        float val = A_s[j][r*4 + c];
        if (c == 3) {
            val -= A_s[j][r*4+0]*Jp_s[j*3+0]
                 + A_s[j][r*4+1]*Jp_s[j*3+1]
                 + A_s[j][r*4+2]*Jp_s[j*3+2];
        }
        ar_ws[(size_t)b*192 + i] = val;
    }
}

// ---------------- kernel 4: per-vertex blendshapes + LBS ----------------
// 1 wave per block: 64 verts x 8 batches. pw/ar staged in LDS.
__global__ __launch_bounds__(64) void k_verts(const float* __restrict__ vt,
                                              const float* __restrict__ sd,
                                              const float* __restrict__ wts,
                                              const float* __restrict__ sp,
                                              const float* __restrict__ ws,
                                              float* __restrict__ out)
{
    __shared__ __align__(16) float pw_s[8*135];
    __shared__ __align__(16) float ar_s[8*192];
    const float* pd = ws + WS_PD;
    const float* pw = ws + WS_PW;
    const float* ar = ws + WS_AR;

    int lane = threadIdx.x;
    int v = blockIdx.x * 64 + lane;
    int b0 = blockIdx.y * 8;

    for (int i = lane; i < 8*135; i += 64) pw_s[i] = pw[(size_t)b0*135 + i];
    for (int i = lane; i < 8*192; i += 64) ar_s[i] = ar[(size_t)b0*192 + i];
    __syncthreads();
    if (v >= NV) return;

    // shape blend
    float acc[8][3];
    {
        float vt3[3] = { vt[v*3], vt[v*3+1], vt[v*3+2] };
        float sd30[30];
        #pragma unroll
        for (int i = 0; i < 30; i++) sd30[i] = sd[v*30 + i];
        #pragma unroll
        for (int bb = 0; bb < 8; bb++) {
            const float* spb = sp + (b0 + bb) * 10;
            #pragma unroll
            for (int c = 0; c < 3; c++) {
                float a = vt3[c];
                #pragma unroll
                for (int s = 0; s < 10; s++) a += spb[s] * sd30[c*10 + s];
                acc[bb][c] = a;
            }
        }
    }

    // pose blend: coalesced pd planes + LDS-broadcast pw
    const float* pd0 = pd + v;
    const float* pd1 = pd + PD_PLANE + v;
    const float* pd2 = pd + 2*PD_PLANE + v;
    #pragma unroll 3
    for (int p = 0; p < 135; p++) {
        float d0 = pd0[p*PDP];
        float d1 = pd1[p*PDP];
        float d2 = pd2[p*PDP];
        #pragma unroll
        for (int bb = 0; bb < 8; bb++) {
            float f = pw_s[bb*135 + p];
            acc[bb][0] += f*d0; acc[bb][1] += f*d1; acc[bb][2] += f*d2;
        }
    }

    // LBS
    float w16[16];
    #pragma unroll
    for (int j = 0; j < 16; j++) w16[j] = wts[v*16 + j];

    #pragma unroll
    for (int bb = 0; bb < 8; bb++) {
        int b = b0 + bb;
        float m[12];
        #pragma unroll
        for (int k = 0; k < 12; k++) m[k] = 0.f;
        #pragma unroll
        for (int j = 0; j < 16; j++) {
            float wj = w16[j];
            const float* a = &ar_s[bb*192 + j*12];
            #pragma unroll
            for (int k = 0; k < 12; k++) m[k] += wj * a[k];
        }
        float x = acc[bb][0], y = acc[bb][1], z = acc[bb][2];
        float o0 = m[0]*x + m[1]*y + m[2]*z  + m[3];
        float o1 = m[4]*x + m[5]*y + m[6]*z  + m[7];
        float o2 = m[8]*x + m[9]*y + m[10]*z + m[11];
        size_t base = OUT_JV + (size_t)b*JVROW + (size_t)(21 + v)*3;
        out[base + 0] = o0; out[base + 1] = o1; out[base + 2] = o2;
        int fp = (v == 320) ? 4 : (v == 443) ? 8 : (v == 672) ? 12
               : (v == 555) ? 16 : (v == 744) ? 20 : -1;
        if (fp >= 0) {
            size_t jb = OUT_JV + (size_t)b*JVROW + (size_t)fp*3;
            out[jb + 0] = o0; out[jb + 1] = o1; out[jb + 2] = o2;
        }
    }
}

// ---------------- kernel 5: faces broadcast (as f32), float4 stores ----------------
__global__ __launch_bounds__(256) void k_faces(const int* __restrict__ faces,
                                               float* __restrict__ out)
{
    const size_t total4 = (size_t)NB * NF * 3 / 4;   // 4,724,736 float4
    size_t idx = (size_t)blockIdx.x * blockDim.x + threadIdx.x;
    float* o = out + OUT_FACES;
    for (size_t i4 = idx; i4 < total4; i4 += (size_t)gridDim.x * blockDim.x) {
        size_t i = i4 * 4;
        int r = (int)(i % (NF*3));
        float4 val;
        val.x = (float)faces[r];
        val.y = (float)faces[(r+1) % (NF*3)];
        val.z = (float)faces[(r+2) % (NF*3)];
        val.w = (float)faces[(r+3) % (NF*3)];
        *reinterpret_cast<float4*>(o + i) = val;
    }
}

extern "C" void kernel_launch(void* const* d_in, const int* in_sizes, int n_in,
                              void* d_out, int out_size, void* d_ws, size_t ws_size,
                              hipStream_t stream)
{
    const float* rot  = (const float*)d_in[0];
    const float* pp   = (const float*)d_in[1];
    const float* sp   = (const float*)d_in[2];
    const float* vt   = (const float*)d_in[3];
    const float* sd   = (const float*)d_in[4];
    const float* pdir = (const float*)d_in[5];
    const float* jr   = (const float*)d_in[6];
    const float* wts  = (const float*)d_in[7];
    const float* hc   = (const float*)d_in[8];
    const float* hm   = (const float*)d_in[9];
    const int*   faces= (const int*)d_in[10];
    float* out = (float*)d_out;
    float* ws  = (float*)d_ws;

    k_consts<<<132, 256, 0, stream>>>(jr, vt, sd, ws);
    k_transpose<<<25, 256, 0, stream>>>(pdir, ws + WS_PD);
    k_batch<<<NB, 64, 0, stream>>>(rot, pp, sp, hc, hm, ws, out);
    k_verts<<<dim3(13, NB/8), 64, 0, stream>>>(vt, sd, wts, sp, ws, out);
    k_faces<<<2048, 256, 0, stream>>>(faces, out);
}

// Round 3
// 111.981 us; speedup vs baseline: 2.3257x; 1.4685x over previous
//
#include <hip/hip_runtime.h>
#include <hip/hip_bf16.h>
#include <math.h>

#define NB 4096
#define NV 778
#define NJ 16
#define NC 30
#define NS 10
#define NF 1538
#define VC3 (NV*3)          // 2334
#define JVROW (799*3)       // 2397 floats per batch in jv
#define KPAD 160            // padded K (135 pose + 10 shape + 1 template)
#define NPAD 2496           // padded vc (13 * 192)

// output float offsets
#define OUT_JV    0
#define OUT_FACES (NB*799*3)                 // 9,818,112
#define OUT_POSES (OUT_FACES + NB*NF*3)      // 28,717,056

// ws layout
#define WS_JT   0                            // 48 f32
#define WS_JS   48                           // 480 f32
#define WS_AR   528                          // NB*192 f32 = 786432
#define WA_BYTES 3147840                     // (528+786432)*4 ; NB*160 bf16 = 1,310,720 B
#define WB_BYTES 4458560                     // NPAD*160 bf16 = 798,720 B
// total ~5.26 MB

typedef __attribute__((ext_vector_type(8))) short bf16x8;
typedef __attribute__((ext_vector_type(4))) float f32x4;

__device__ const int d_pos16[16] = {0,1,2,3,5,6,7,9,10,11,13,14,15,17,18,19};

// ---------------- kernel 1: batch-independent constants ----------------
__global__ __launch_bounds__(256) void k_consts(const float* __restrict__ jr,
                                                const float* __restrict__ vt,
                                                const float* __restrict__ sd,
                                                float* __restrict__ ws)
{
    int w = (blockIdx.x * blockDim.x + threadIdx.x) >> 6;
    int lane = threadIdx.x & 63;
    if (w >= 528) return;
    float acc = 0.f;
    if (w < 48) {
        int j = w / 3, c = w % 3;
        for (int v = lane; v < NV; v += 64) acc += jr[j*NV + v] * vt[v*3 + c];
    } else {
        int q = w - 48;                  // q = (j*3+c)*10 + s
        int j = q / 30, rem = q % 30, c = rem / 10, s = rem % 10;
        for (int v = lane; v < NV; v += 64) acc += jr[j*NV + v] * sd[v*30 + c*10 + s];
    }
    for (int off = 32; off; off >>= 1) acc += __shfl_down(acc, off);
    if (lane == 0) ws[w] = acc;
}

// ---------------- kernel 2: build B matrix [NPAD rows][160 k] bf16 ----------------
// row vc: k<135 -> posedirs[vc][k]; 135..144 -> shapedirs[v][c][k-135]; 145 -> v_template[vc]
__global__ __launch_bounds__(256) void k_buildB(const float* __restrict__ pdin,
                                                const float* __restrict__ sd,
                                                const float* __restrict__ vt,
                                                __hip_bfloat16* __restrict__ WB)
{
    int idx = blockIdx.x * 256 + threadIdx.x;
    if (idx >= NPAD * KPAD) return;
    int row = idx / KPAD, k = idx % KPAD;
    float val = 0.f;
    if (row < VC3) {
        if (k < 135) val = pdin[(size_t)row*135 + k];
        else if (k < 145) { int v = row/3, c = row%3; val = sd[v*30 + c*10 + (k-135)]; }
        else if (k == 145) val = vt[row];
    }
    WB[idx] = __float2bfloat16(val);
}

// ---------------- kernel 3: per-batch pose/FK + A-row (bf16) ----------------
__global__ __launch_bounds__(64) void k_batch(const float* __restrict__ rot,
                                              const float* __restrict__ pp,
                                              const float* __restrict__ sp,
                                              const float* __restrict__ hc,
                                              const float* __restrict__ hm,
                                              float* __restrict__ ws,
                                              float* __restrict__ out)
{
    __shared__ float poses_s[48];
    __shared__ float R_s[16][9];
    __shared__ float Jp_s[48];
    __shared__ float A_s[16][12];
    float* ar_ws = ws + WS_AR;
    __hip_bfloat16* WA = (__hip_bfloat16*)((char*)ws + WA_BYTES);

    int b = blockIdx.x, t = threadIdx.x;

    if (t < 3) poses_s[t] = rot[b*3 + t];
    if (t < 45) {
        float a = hm[t];
        for (int s = 0; s < NC; s++) a += pp[b*NC + s] * hc[s*45 + t];
        poses_s[3 + t] = a;
    }
    __syncthreads();
    if (t < 48) out[OUT_POSES + (size_t)b*48 + t] = poses_s[t];

    if (t < 48) {
        float a = ws[WS_JT + t];
        const float* js = ws + WS_JS + t*10;
        float acc = a;
        for (int s = 0; s < NS; s++) acc += js[s] * sp[b*NS + s];
        Jp_s[t] = acc;
    }
    if (t < 16) {
        float x = poses_s[t*3], y = poses_s[t*3+1], z = poses_s[t*3+2];
        float th = sqrtf(x*x + y*y + z*z + 1e-8f);
        float kx = x/th, ky = y/th, kz = z/th;
        float s = sinf(th), c = cosf(th), oc = 1.f - c;
        float* R = R_s[t];
        R[0] = 1.f + oc*(-(ky*ky + kz*kz));
        R[1] = -s*kz + oc*(kx*ky);
        R[2] =  s*ky + oc*(kx*kz);
        R[3] =  s*kz + oc*(kx*ky);
        R[4] = 1.f + oc*(-(kx*kx + kz*kz));
        R[5] = -s*kx + oc*(ky*kz);
        R[6] = -s*ky + oc*(kx*kz);
        R[7] =  s*kx + oc*(ky*kz);
        R[8] = 1.f + oc*(-(kx*kx + ky*ky));
    }
    __syncthreads();

    // A-matrix row for GEMM: [pw(135) | sp(10) | 1 | zeros]
    for (int i = t; i < KPAD; i += 64) {
        float val;
        if (i < 135) {
            int j = 1 + i/9, e = i % 9;
            val = R_s[j][e] - ((e == 0 || e == 4 || e == 8) ? 1.f : 0.f);
        } else if (i < 145) val = sp[b*NS + (i - 135)];
        else if (i == 145) val = 1.0f;
        else val = 0.f;
        WA[(size_t)b*KPAD + i] = __float2bfloat16(val);
    }

    if (t < 12) {
        int r = t >> 2, c = t & 3;
        A_s[0][t] = (c < 3) ? R_s[0][r*3 + c] : Jp_s[r];
    }
    __syncthreads();
    const int par[16] = {0,0,1,2,0,4,5,0,7,8,0,10,11,0,13,14};
    #pragma unroll
    for (int i = 1; i < 16; i++) {
        int p = par[i];
        if (t < 12) {
            int r = t >> 2, c = t & 3;
            float val;
            if (c < 3) {
                val = A_s[p][r*4+0]*R_s[i][0*3+c]
                    + A_s[p][r*4+1]*R_s[i][1*3+c]
                    + A_s[p][r*4+2]*R_s[i][2*3+c];
            } else {
                float t0 = Jp_s[i*3+0] - Jp_s[p*3+0];
                float t1 = Jp_s[i*3+1] - Jp_s[p*3+1];
                float t2 = Jp_s[i*3+2] - Jp_s[p*3+2];
                val = A_s[p][r*4+0]*t0 + A_s[p][r*4+1]*t1
                    + A_s[p][r*4+2]*t2 + A_s[p][r*4+3];
            }
            A_s[i][t] = val;
        }
        __syncthreads();
    }

    if (t < 48) {
        int j = t / 3, r = t % 3;
        out[OUT_JV + (size_t)b*JVROW + d_pos16[j]*3 + r] = A_s[j][r*4 + 3];
    }
    for (int i = t; i < 192; i += 64) {
        int j = i / 12, rc = i % 12, r = rc >> 2, c = rc & 3;
        float val = A_s[j][r*4 + c];
        if (c == 3) {
            val -= A_s[j][r*4+0]*Jp_s[j*3+0]
                 + A_s[j][r*4+1]*Jp_s[j*3+1]
                 + A_s[j][r*4+2]*Jp_s[j*3+2];
        }
        ar_ws[(size_t)b*192 + i] = val;
    }
}

// ---------------- kernel 4: fused GEMM (v_posed) + LBS epilogue ----------------
// Tile: 64 batches x 192 cols (64 verts), K=160 single stage. 512 thr = 8 waves (2m x 4n).
__global__ __launch_bounds__(512) void k_gemm_lbs(const ushort* __restrict__ WA,
                                                  const ushort* __restrict__ WB,
                                                  const float* __restrict__ ar,
                                                  const float* __restrict__ wts,
                                                  float* __restrict__ out)
{
    // LDS: phase1 A[64][168] + B[192][168] bf16 = 86016 B; phase2 C[64][195] f32 = 49920 B (aliased)
    __shared__ __align__(16) char smem[64*168*2 + 192*168*2];
    ushort (*As)[168] = (ushort(*)[168])smem;
    ushort (*Bs)[168] = (ushort(*)[168])(smem + 64*168*2);
    float  (*Cs)[195] = (float(*)[195])smem;

    int tid = threadIdx.x;
    int bx = blockIdx.x, by = blockIdx.y;
    int n0 = bx * 192, b0 = by * 64;

    // stage A (64 rows x 20 chunks of 8 bf16) and B (192 x 20)
    for (int i = tid; i < 64*20; i += 512) {
        int r = i / 20, c = i % 20;
        uint4 v4 = *(const uint4*)(WA + (size_t)(b0 + r)*KPAD + c*8);
        *(uint4*)&As[r][c*8] = v4;
    }
    for (int i = tid; i < 192*20; i += 512) {
        int r = i / 20, c = i % 20;
        uint4 v4 = *(const uint4*)(WB + (size_t)(n0 + r)*KPAD + c*8);
        *(uint4*)&Bs[r][c*8] = v4;
    }
    __syncthreads();

    int wv = __builtin_amdgcn_readfirstlane(tid >> 6);   // wave id 0..7 (uniform -> SGPR)
    int lane = tid & 63;
    int wm = wv >> 2;          // 0..1 : 32-batch half
    int wn = wv & 3;           // 0..3 : 48-col quarter
    int l15 = lane & 15, lk = (lane >> 4) * 8;

    f32x4 acc[2][3] = {};
    #pragma unroll
    for (int ks = 0; ks < 5; ks++) {
        bf16x8 a[2], bfr[3];
        #pragma unroll
        for (int mi = 0; mi < 2; mi++)
            a[mi] = *(bf16x8*)&As[wm*32 + mi*16 + l15][ks*32 + lk];
        #pragma unroll
        for (int ni = 0; ni < 3; ni++)
            bfr[ni] = *(bf16x8*)&Bs[wn*48 + ni*16 + l15][ks*32 + lk];
        #pragma unroll
        for (int mi = 0; mi < 2; mi++)
            #pragma unroll
            for (int ni = 0; ni < 3; ni++)
                acc[mi][ni] = __builtin_amdgcn_mfma_f32_16x16x32_bf16(a[mi], bfr[ni], acc[mi][ni], 0, 0, 0);
    }
    __syncthreads();

    // scatter C tile to LDS: row = batch-local, col = n-local
    #pragma unroll
    for (int mi = 0; mi < 2; mi++)
        #pragma unroll
        for (int ni = 0; ni < 3; ni++)
            #pragma unroll
            for (int r = 0; r < 4; r++)
                Cs[wm*32 + mi*16 + 4*(lane>>4) + r][wn*48 + ni*16 + l15] = acc[mi][ni][r];
    __syncthreads();

    // LBS epilogue: lane = local vertex (64), each wave does 8 batches
    int vloc = lane;
    int v = bx*64 + vloc;
    bool vok = (v < NV);
    float w16[16];
    if (vok) {
        uint4 q0 = *(const uint4*)(wts + (size_t)v*16);
        uint4 q1 = *(const uint4*)(wts + (size_t)v*16 + 4);
        uint4 q2 = *(const uint4*)(wts + (size_t)v*16 + 8);
        uint4 q3 = *(const uint4*)(wts + (size_t)v*16 + 12);
        w16[0]=__uint_as_float(q0.x); w16[1]=__uint_as_float(q0.y); w16[2]=__uint_as_float(q0.z); w16[3]=__uint_as_float(q0.w);
        w16[4]=__uint_as_float(q1.x); w16[5]=__uint_as_float(q1.y); w16[6]=__uint_as_float(q1.z); w16[7]=__uint_as_float(q1.w);
        w16[8]=__uint_as_float(q2.x); w16[9]=__uint_as_float(q2.y); w16[10]=__uint_as_float(q2.z); w16[11]=__uint_as_float(q2.w);
        w16[12]=__uint_as_float(q3.x); w16[13]=__uint_as_float(q3.y); w16[14]=__uint_as_float(q3.z); w16[15]=__uint_as_float(q3.w);
    } else {
        #pragma unroll
        for (int j = 0; j < 16; j++) w16[j] = 0.f;
    }

    int fp = (v == 320) ? 4 : (v == 443) ? 8 : (v == 672) ? 12
           : (v == 555) ? 16 : (v == 744) ? 20 : -1;

    for (int bi = 0; bi < 8; bi++) {
        int bloc = wv*8 + bi;
        int b = b0 + bloc;
        const float* arb = ar + (size_t)b * 192;   // wave-uniform -> s_load
        float x = Cs[bloc][3*vloc + 0];
        float y = Cs[bloc][3*vloc + 1];
        float z = Cs[bloc][3*vloc + 2];
        float m[12];
        #pragma unroll
        for (int k = 0; k < 12; k++) m[k] = 0.f;
        #pragma unroll
        for (int j = 0; j < 16; j++) {
            float wj = w16[j];
            #pragma unroll
            for (int k = 0; k < 12; k++) m[k] += wj * arb[j*12 + k];
        }
        if (vok) {
            float o0 = m[0]*x + m[1]*y + m[2]*z  + m[3];
            float o1 = m[4]*x + m[5]*y + m[6]*z  + m[7];
            float o2 = m[8]*x + m[9]*y + m[10]*z + m[11];
            size_t base = OUT_JV + (size_t)b*JVROW + (size_t)(21 + v)*3;
            out[base + 0] = o0; out[base + 1] = o1; out[base + 2] = o2;
            if (fp >= 0) {
                size_t jb = OUT_JV + (size_t)b*JVROW + (size_t)fp*3;
                out[jb + 0] = o0; out[jb + 1] = o1; out[jb + 2] = o2;
            }
        }
    }
}

// ---------------- kernel 5: faces broadcast (as f32), float4 stores ----------------
__global__ __launch_bounds__(256) void k_faces(const int* __restrict__ faces,
                                               float* __restrict__ out)
{
    const size_t total4 = (size_t)NB * NF * 3 / 4;
    size_t idx = (size_t)blockIdx.x * blockDim.x + threadIdx.x;
    float* o = out + OUT_FACES;
    for (size_t i4 = idx; i4 < total4; i4 += (size_t)gridDim.x * blockDim.x) {
        size_t i = i4 * 4;
        int r = (int)(i % (NF*3));
        float4 val;
        val.x = (float)faces[r];
        val.y = (float)faces[(r+1) % (NF*3)];
        val.z = (float)faces[(r+2) % (NF*3)];
        val.w = (float)faces[(r+3) % (NF*3)];
        *reinterpret_cast<float4*>(o + i) = val;
    }
}

extern "C" void kernel_launch(void* const* d_in, const int* in_sizes, int n_in,
                              void* d_out, int out_size, void* d_ws, size_t ws_size,
                              hipStream_t stream)
{
    const float* rot  = (const float*)d_in[0];
    const float* pp   = (const float*)d_in[1];
    const float* sp   = (const float*)d_in[2];
    const float* vt   = (const float*)d_in[3];
    const float* sd   = (const float*)d_in[4];
    const float* pdir = (const float*)d_in[5];
    const float* jr   = (const float*)d_in[6];
    const float* wts  = (const float*)d_in[7];
    const float* hc   = (const float*)d_in[8];
    const float* hm   = (const float*)d_in[9];
    const int*   faces= (const int*)d_in[10];
    float* out = (float*)d_out;
    float* ws  = (float*)d_ws;

    const ushort* WA = (const ushort*)((char*)d_ws + WA_BYTES);
    const ushort* WB = (const ushort*)((char*)d_ws + WB_BYTES);

    k_consts<<<132, 256, 0, stream>>>(jr, vt, sd, ws);
    k_buildB<<<(NPAD*KPAD + 255)/256, 256, 0, stream>>>(pdir, sd, vt,
                (__hip_bfloat16*)((char*)d_ws + WB_BYTES));
    k_batch<<<NB, 64, 0, stream>>>(rot, pp, sp, hc, hm, ws, out);
    k_gemm_lbs<<<dim3(13, NB/64), 512, 0, stream>>>(WA, WB, ws + WS_AR, wts, out);
    k_faces<<<2048, 256, 0, stream>>>(faces, out);
}

// Round 4
// 74.854 us; speedup vs baseline: 3.4793x; 1.4960x over previous
//
#include <hip/hip_runtime.h>
#include <hip/hip_bf16.h>
#include <math.h>

#define NB 4096
#define NV 778
#define NJ 16
#define NC 30
#define NS 10
#define NF 1538
#define VC3 (NV*3)          // 2334
#define JVROW (799*3)       // 2397 floats per batch in jv
#define KPAD 160            // padded K (135 pose + 10 shape + 1 template)
#define NPAD 2496           // padded vc (13 * 192)

// output float offsets
#define OUT_JV    0
#define OUT_FACES (NB*799*3)                 // 9,818,112
#define OUT_POSES (OUT_FACES + NB*NF*3)      // 28,717,056

// ws layout
#define WS_JT   0                            // 48 f32
#define WS_JS   48                           // 480 f32
#define WS_AR   528                          // NB*192 f32 = 786432
#define WA_BYTES 3147840                     // NB*160 bf16 = 1,310,720 B
#define WB_BYTES 4458560                     // NPAD*160 bf16 = 798,720 B
// end 5,257,280 B

typedef __attribute__((ext_vector_type(8))) short bf16x8;
typedef __attribute__((ext_vector_type(4))) float f32x4;

__device__ const int d_pos16[16] = {0,1,2,3,5,6,7,9,10,11,13,14,15,17,18,19};

// ---------------- kernel 1: batch-independent constants ----------------
__global__ __launch_bounds__(256) void k_consts(const float* __restrict__ jr,
                                                const float* __restrict__ vt,
                                                const float* __restrict__ sd,
                                                float* __restrict__ ws)
{
    int w = (blockIdx.x * blockDim.x + threadIdx.x) >> 6;
    int lane = threadIdx.x & 63;
    if (w >= 528) return;
    float acc = 0.f;
    if (w < 48) {
        int j = w / 3, c = w % 3;
        for (int v = lane; v < NV; v += 64) acc += jr[j*NV + v] * vt[v*3 + c];
    } else {
        int q = w - 48;
        int j = q / 30, rem = q % 30, c = rem / 10, s = rem % 10;
        for (int v = lane; v < NV; v += 64) acc += jr[j*NV + v] * sd[v*30 + c*10 + s];
    }
    for (int off = 32; off; off >>= 1) acc += __shfl_down(acc, off);
    if (lane == 0) ws[w] = acc;
}

// ---------------- kernel 2: build B matrix [NPAD rows][160 k] bf16 ----------------
__global__ __launch_bounds__(256) void k_buildB(const float* __restrict__ pdin,
                                                const float* __restrict__ sd,
                                                const float* __restrict__ vt,
                                                __hip_bfloat16* __restrict__ WB)
{
    int idx = blockIdx.x * 256 + threadIdx.x;
    if (idx >= NPAD * KPAD) return;
    int row = idx / KPAD, k = idx % KPAD;
    float val = 0.f;
    if (row < VC3) {
        if (k < 135) val = pdin[(size_t)row*135 + k];
        else if (k < 145) { int v = row/3, c = row%3; val = sd[v*30 + c*10 + (k-135)]; }
        else if (k == 145) val = vt[row];
    }
    WB[idx] = __float2bfloat16(val);
}

// ---------------- kernel 3: per-batch pose/FK + A-row (bf16) ----------------
__global__ __launch_bounds__(64) void k_batch(const float* __restrict__ rot,
                                              const float* __restrict__ pp,
                                              const float* __restrict__ sp,
                                              const float* __restrict__ hc,
                                              const float* __restrict__ hm,
                                              float* __restrict__ ws,
                                              float* __restrict__ out)
{
    __shared__ float poses_s[48];
    __shared__ float R_s[16][9];
    __shared__ float Jp_s[48];
    __shared__ float A_s[16][12];
    float* ar_ws = ws + WS_AR;
    __hip_bfloat16* WA = (__hip_bfloat16*)((char*)ws + WA_BYTES);

    int b = blockIdx.x, t = threadIdx.x;

    if (t < 3) poses_s[t] = rot[b*3 + t];
    if (t < 45) {
        float a = hm[t];
        for (int s = 0; s < NC; s++) a += pp[b*NC + s] * hc[s*45 + t];
        poses_s[3 + t] = a;
    }
    __syncthreads();
    if (t < 48) out[OUT_POSES + (size_t)b*48 + t] = poses_s[t];

    if (t < 48) {
        float a = ws[WS_JT + t];
        const float* js = ws + WS_JS + t*10;
        float acc = a;
        for (int s = 0; s < NS; s++) acc += js[s] * sp[b*NS + s];
        Jp_s[t] = acc;
    }
    if (t < 16) {
        float x = poses_s[t*3], y = poses_s[t*3+1], z = poses_s[t*3+2];
        float th = sqrtf(x*x + y*y + z*z + 1e-8f);
        float kx = x/th, ky = y/th, kz = z/th;
        float s = sinf(th), c = cosf(th), oc = 1.f - c;
        float* R = R_s[t];
        R[0] = 1.f + oc*(-(ky*ky + kz*kz));
        R[1] = -s*kz + oc*(kx*ky);
        R[2] =  s*ky + oc*(kx*kz);
        R[3] =  s*kz + oc*(kx*ky);
        R[4] = 1.f + oc*(-(kx*kx + kz*kz));
        R[5] = -s*kx + oc*(ky*kz);
        R[6] = -s*ky + oc*(kx*kz);
        R[7] =  s*kx + oc*(ky*kz);
        R[8] = 1.f + oc*(-(kx*kx + ky*ky));
    }
    __syncthreads();

    // A-matrix row for GEMM: [pw(135) | sp(10) | 1 | zeros]
    for (int i = t; i < KPAD; i += 64) {
        float val;
        if (i < 135) {
            int j = 1 + i/9, e = i % 9;
            val = R_s[j][e] - ((e == 0 || e == 4 || e == 8) ? 1.f : 0.f);
        } else if (i < 145) val = sp[b*NS + (i - 135)];
        else if (i == 145) val = 1.0f;
        else val = 0.f;
        WA[(size_t)b*KPAD + i] = __float2bfloat16(val);
    }

    if (t < 12) {
        int r = t >> 2, c = t & 3;
        A_s[0][t] = (c < 3) ? R_s[0][r*3 + c] : Jp_s[r];
    }
    __syncthreads();
    const int par[16] = {0,0,1,2,0,4,5,0,7,8,0,10,11,0,13,14};
    #pragma unroll
    for (int i = 1; i < 16; i++) {
        int p = par[i];
        if (t < 12) {
            int r = t >> 2, c = t & 3;
            float val;
            if (c < 3) {
                val = A_s[p][r*4+0]*R_s[i][0*3+c]
                    + A_s[p][r*4+1]*R_s[i][1*3+c]
                    + A_s[p][r*4+2]*R_s[i][2*3+c];
            } else {
                float t0 = Jp_s[i*3+0] - Jp_s[p*3+0];
                float t1 = Jp_s[i*3+1] - Jp_s[p*3+1];
                float t2 = Jp_s[i*3+2] - Jp_s[p*3+2];
                val = A_s[p][r*4+0]*t0 + A_s[p][r*4+1]*t1
                    + A_s[p][r*4+2]*t2 + A_s[p][r*4+3];
            }
            A_s[i][t] = val;
        }
        __syncthreads();
    }

    if (t < 48) {
        int j = t / 3, r = t % 3;
        out[OUT_JV + (size_t)b*JVROW + d_pos16[j]*3 + r] = A_s[j][r*4 + 3];
    }
    for (int i = t; i < 192; i += 64) {
        int j = i / 12, rc = i % 12, r = rc >> 2, c = rc & 3;
        float val = A_s[j][r*4 + c];
        if (c == 3) {
            val -= A_s[j][r*4+0]*Jp_s[j*3+0]
                 + A_s[j][r*4+1]*Jp_s[j*3+1]
                 + A_s[j][r*4+2]*Jp_s[j*3+2];
        }
        ar_ws[(size_t)b*192 + i] = val;
    }
}

// ---------------- kernel 4: fused GEMM (v_posed) + LBS epilogue ----------------
// Tile: 64 batches x 192 cols. Fragments direct from global (L2-hot), LDS only
// for C redistribution (64 x 196 f32 = 50 KB -> 2 blocks/CU).
__global__ __launch_bounds__(512, 4) void k_gemm_lbs(const ushort* __restrict__ WA,
                                                     const ushort* __restrict__ WB,
                                                     const float* __restrict__ ar,
                                                     const float* __restrict__ wts,
                                                     float* __restrict__ out)
{
    __shared__ __align__(16) float Cs[64][196];

    // XCD-bijective swizzle: 832 blocks = 8 XCDs x 104; keep same-by blocks on one XCD
    int bid = blockIdx.x;
    int swz = (bid & 7) * 104 + (bid >> 3);
    int bx = swz % 13, by = swz / 13;
    int n0 = bx * 192, b0 = by * 64;

    int tid = threadIdx.x;
    int wv = __builtin_amdgcn_readfirstlane(tid >> 6);   // wave id 0..7
    int lane = tid & 63;
    int wm = wv >> 2;          // 0..1 : 32-batch half
    int wn = wv & 3;           // 0..3 : 48-col quarter
    int l15 = lane & 15, lk = (lane >> 4) * 8;

    const ushort* Abase = WA + (size_t)(b0 + wm*32 + l15)*KPAD + lk;
    const ushort* Bbase = WB + (size_t)(n0 + wn*48 + l15)*KPAD + lk;

    f32x4 acc[2][3] = {};
    #pragma unroll
    for (int ks = 0; ks < 5; ks++) {
        bf16x8 a[2], bf[3];
        #pragma unroll
        for (int mi = 0; mi < 2; mi++)
            a[mi] = *(const bf16x8*)(Abase + (size_t)mi*16*KPAD + ks*32);
        #pragma unroll
        for (int ni = 0; ni < 3; ni++)
            bf[ni] = *(const bf16x8*)(Bbase + (size_t)ni*16*KPAD + ks*32);
        #pragma unroll
        for (int mi = 0; mi < 2; mi++)
            #pragma unroll
            for (int ni = 0; ni < 3; ni++)
                acc[mi][ni] = __builtin_amdgcn_mfma_f32_16x16x32_bf16(a[mi], bf[ni], acc[mi][ni], 0, 0, 0);
    }

    // scatter C tile to LDS (row=batch-local, col=n-local; stride 196 -> conflict-free)
    #pragma unroll
    for (int mi = 0; mi < 2; mi++)
        #pragma unroll
        for (int ni = 0; ni < 3; ni++)
            #pragma unroll
            for (int r = 0; r < 4; r++)
                Cs[wm*32 + mi*16 + 4*(lane>>4) + r][wn*48 + ni*16 + l15] = acc[mi][ni][r];
    __syncthreads();

    // LBS epilogue: lane = local vertex, each wave does 8 batches
    int vloc = lane;
    int v = bx*64 + vloc;
    bool vok = (v < NV);
    float w16[16];
    if (vok) {
        #pragma unroll
        for (int j = 0; j < 16; j++) w16[j] = wts[(size_t)v*16 + j];
    } else {
        #pragma unroll
        for (int j = 0; j < 16; j++) w16[j] = 0.f;
    }

    int fp = (v == 320) ? 4 : (v == 443) ? 8 : (v == 672) ? 12
           : (v == 555) ? 16 : (v == 744) ? 20 : -1;

    for (int bi = 0; bi < 8; bi++) {
        int bloc = wv*8 + bi;
        int b = b0 + bloc;
        const float* arb = ar + (size_t)b * 192;   // wave-uniform -> s_load
        float x = Cs[bloc][3*vloc + 0];
        float y = Cs[bloc][3*vloc + 1];
        float z = Cs[bloc][3*vloc + 2];
        float m[12];
        #pragma unroll
        for (int k = 0; k < 12; k++) m[k] = 0.f;
        #pragma unroll
        for (int j = 0; j < 16; j++) {
            float wj = w16[j];
            #pragma unroll
            for (int k = 0; k < 12; k++) m[k] += wj * arb[j*12 + k];
        }
        if (vok) {
            float o0 = m[0]*x + m[1]*y + m[2]*z  + m[3];
            float o1 = m[4]*x + m[5]*y + m[6]*z  + m[7];
            float o2 = m[8]*x + m[9]*y + m[10]*z + m[11];
            size_t base = OUT_JV + (size_t)b*JVROW + (size_t)(21 + v)*3;
            out[base + 0] = o0; out[base + 1] = o1; out[base + 2] = o2;
            if (fp >= 0) {
                size_t jb = OUT_JV + (size_t)b*JVROW + (size_t)fp*3;
                out[jb + 0] = o0; out[jb + 1] = o1; out[jb + 2] = o2;
            }
        }
    }
}

// ---------------- kernel 5: faces broadcast (as f32), float2 stores, no div ----------------
__global__ __launch_bounds__(256) void k_faces(const int* __restrict__ faces,
                                               float* __restrict__ out)
{
    int b = blockIdx.x;
    float* o = out + OUT_FACES + (size_t)b * (NF*3);
    for (int i = threadIdx.x; i < (NF*3)/2; i += 256) {
        float2 val;
        val.x = (float)faces[2*i];
        val.y = (float)faces[2*i + 1];
        *reinterpret_cast<float2*>(o + 2*i) = val;
    }
}

extern "C" void kernel_launch(void* const* d_in, const int* in_sizes, int n_in,
                              void* d_out, int out_size, void* d_ws, size_t ws_size,
                              hipStream_t stream)
{
    const float* rot  = (const float*)d_in[0];
    const float* pp   = (const float*)d_in[1];
    const float* sp   = (const float*)d_in[2];
    const float* vt   = (const float*)d_in[3];
    const float* sd   = (const float*)d_in[4];
    const float* pdir = (const float*)d_in[5];
    const float* jr   = (const float*)d_in[6];
    const float* wts  = (const float*)d_in[7];
    const float* hc   = (const float*)d_in[8];
    const float* hm   = (const float*)d_in[9];
    const int*   faces= (const int*)d_in[10];
    float* out = (float*)d_out;
    float* ws  = (float*)d_ws;

    const ushort* WA = (const ushort*)((char*)d_ws + WA_BYTES);
    const ushort* WB = (const ushort*)((char*)d_ws + WB_BYTES);

    k_consts<<<132, 256, 0, stream>>>(jr, vt, sd, ws);
    k_buildB<<<(NPAD*KPAD + 255)/256, 256, 0, stream>>>(pdir, sd, vt,
                (__hip_bfloat16*)((char*)d_ws + WB_BYTES));
    k_batch<<<NB, 64, 0, stream>>>(rot, pp, sp, hc, hm, ws, out);
    k_gemm_lbs<<<13 * (NB/64), 512, 0, stream>>>(WA, WB, ws + WS_AR, wts, out);
    k_faces<<<NB, 256, 0, stream>>>(faces, out);
}

// Round 5
// 71.001 us; speedup vs baseline: 3.6680x; 1.0543x over previous
//
#include <hip/hip_runtime.h>
#include <hip/hip_bf16.h>
#include <math.h>

#define NB 4096
#define NV 778
#define NJ 16
#define NC 30
#define NS 10
#define NF 1538
#define VC3 (NV*3)          // 2334
#define JVROW (799*3)       // 2397 floats per batch in jv
#define KPAD 160            // padded K (135 pose + 10 shape + 1 template)
#define NPAD 2496           // padded vc (13 * 192)
#define FROW (NF*3)         // 4614

// output float offsets
#define OUT_JV    0
#define OUT_FACES (NB*799*3)                 // 9,818,112
#define OUT_POSES (OUT_FACES + NB*NF*3)      // 28,717,056

// ws layout
#define WS_JT   0                            // 48 f32
#define WS_JS   48                           // 480 f32
#define WS_AR   528                          // NB*192 f32 = 786432
#define WA_BYTES 3147840                     // NB*160 bf16 = 1,310,720 B
#define WB_BYTES 4458560                     // NPAD*160 bf16 = 798,720 B
// end 5,257,280 B

typedef __attribute__((ext_vector_type(8))) short bf16x8;
typedef __attribute__((ext_vector_type(4))) float f32x4;

__device__ const int d_pos16[16] = {0,1,2,3,5,6,7,9,10,11,13,14,15,17,18,19};

// ---------------- kernel 1: consts (blocks 0..131) + buildB (blocks 132..1691) ----------------
__global__ __launch_bounds__(256) void k_prep(const float* __restrict__ jr,
                                              const float* __restrict__ vt,
                                              const float* __restrict__ sd,
                                              const float* __restrict__ pdin,
                                              float* __restrict__ ws,
                                              __hip_bfloat16* __restrict__ WB)
{
    int blk = blockIdx.x;
    if (blk < 132) {
        int w = (blk * 256 + threadIdx.x) >> 6;
        int lane = threadIdx.x & 63;
        if (w >= 528) return;
        float acc = 0.f;
        if (w < 48) {
            int j = w / 3, c = w % 3;
            for (int v = lane; v < NV; v += 64) acc += jr[j*NV + v] * vt[v*3 + c];
        } else {
            int q = w - 48;
            int j = q / 30, rem = q % 30, c = rem / 10, s = rem % 10;
            for (int v = lane; v < NV; v += 64) acc += jr[j*NV + v] * sd[v*30 + c*10 + s];
        }
        for (int off = 32; off; off >>= 1) acc += __shfl_down(acc, off);
        if (lane == 0) ws[w] = acc;
    } else {
        int idx = (blk - 132) * 256 + threadIdx.x;
        if (idx >= NPAD * KPAD) return;
        int row = idx / KPAD, k = idx % KPAD;
        float val = 0.f;
        if (row < VC3) {
            if (k < 135) val = pdin[(size_t)row*135 + k];
            else if (k < 145) { int v = row/3, c = row%3; val = sd[v*30 + c*10 + (k-135)]; }
            else if (k == 145) val = vt[row];
        }
        WB[idx] = __float2bfloat16(val);
    }
}

// ---------------- kernel 2: per-batch pose/FK + A-row (bf16) + faces row ----------------
__global__ __launch_bounds__(64) void k_batch(const float* __restrict__ rot,
                                              const float* __restrict__ pp,
                                              const float* __restrict__ sp,
                                              const float* __restrict__ hc,
                                              const float* __restrict__ hm,
                                              const int* __restrict__ faces,
                                              float* __restrict__ ws,
                                              float* __restrict__ out)
{
    __shared__ float poses_s[48];
    __shared__ float R_s[16][9];
    __shared__ float Jp_s[48];
    __shared__ float A_s[16][12];
    float* ar_ws = ws + WS_AR;
    __hip_bfloat16* WA = (__hip_bfloat16*)((char*)ws + WA_BYTES);

    int b = blockIdx.x, t = threadIdx.x;

    if (t < 3) poses_s[t] = rot[b*3 + t];
    if (t < 45) {
        float a = hm[t];
        for (int s = 0; s < NC; s++) a += pp[b*NC + s] * hc[s*45 + t];
        poses_s[3 + t] = a;
    }
    __syncthreads();
    if (t < 48) out[OUT_POSES + (size_t)b*48 + t] = poses_s[t];

    // faces broadcast row for this batch (pure writes; hides under FK latency)
    {
        float* fo = out + OUT_FACES + (size_t)b * FROW;
        for (int i = t; i < FROW/2; i += 64) {
            float2 val;
            val.x = (float)faces[2*i];
            val.y = (float)faces[2*i + 1];
            *reinterpret_cast<float2*>(fo + 2*i) = val;
        }
    }

    if (t < 48) {
        float a = ws[WS_JT + t];
        const float* js = ws + WS_JS + t*10;
        float acc = a;
        for (int s = 0; s < NS; s++) acc += js[s] * sp[b*NS + s];
        Jp_s[t] = acc;
    }
    if (t < 16) {
        float x = poses_s[t*3], y = poses_s[t*3+1], z = poses_s[t*3+2];
        float th = sqrtf(x*x + y*y + z*z + 1e-8f);
        float kx = x/th, ky = y/th, kz = z/th;
        float s = sinf(th), c = cosf(th), oc = 1.f - c;
        float* R = R_s[t];
        R[0] = 1.f + oc*(-(ky*ky + kz*kz));
        R[1] = -s*kz + oc*(kx*ky);
        R[2] =  s*ky + oc*(kx*kz);
        R[3] =  s*kz + oc*(kx*ky);
        R[4] = 1.f + oc*(-(kx*kx + kz*kz));
        R[5] = -s*kx + oc*(ky*kz);
        R[6] = -s*ky + oc*(kx*kz);
        R[7] =  s*kx + oc*(ky*kz);
        R[8] = 1.f + oc*(-(kx*kx + ky*ky));
    }
    __syncthreads();

    // A-matrix row for GEMM: [pw(135) | sp(10) | 1 | zeros]
    for (int i = t; i < KPAD; i += 64) {
        float val;
        if (i < 135) {
            int j = 1 + i/9, e = i % 9;
            val = R_s[j][e] - ((e == 0 || e == 4 || e == 8) ? 1.f : 0.f);
        } else if (i < 145) val = sp[b*NS + (i - 135)];
        else if (i == 145) val = 1.0f;
        else val = 0.f;
        WA[(size_t)b*KPAD + i] = __float2bfloat16(val);
    }

    if (t < 12) {
        int r = t >> 2, c = t & 3;
        A_s[0][t] = (c < 3) ? R_s[0][r*3 + c] : Jp_s[r];
    }
    __syncthreads();
    const int par[16] = {0,0,1,2,0,4,5,0,7,8,0,10,11,0,13,14};
    #pragma unroll
    for (int i = 1; i < 16; i++) {
        int p = par[i];
        if (t < 12) {
            int r = t >> 2, c = t & 3;
            float val;
            if (c < 3) {
                val = A_s[p][r*4+0]*R_s[i][0*3+c]
                    + A_s[p][r*4+1]*R_s[i][1*3+c]
                    + A_s[p][r*4+2]*R_s[i][2*3+c];
            } else {
                float t0 = Jp_s[i*3+0] - Jp_s[p*3+0];
                float t1 = Jp_s[i*3+1] - Jp_s[p*3+1];
                float t2 = Jp_s[i*3+2] - Jp_s[p*3+2];
                val = A_s[p][r*4+0]*t0 + A_s[p][r*4+1]*t1
                    + A_s[p][r*4+2]*t2 + A_s[p][r*4+3];
            }
            A_s[i][t] = val;
        }
        __syncthreads();
    }

    if (t < 48) {
        int j = t / 3, r = t % 3;
        out[OUT_JV + (size_t)b*JVROW + d_pos16[j]*3 + r] = A_s[j][r*4 + 3];
    }
    for (int i = t; i < 192; i += 64) {
        int j = i / 12, rc = i % 12, r = rc >> 2, c = rc & 3;
        float val = A_s[j][r*4 + c];
        if (c == 3) {
            val -= A_s[j][r*4+0]*Jp_s[j*3+0]
                 + A_s[j][r*4+1]*Jp_s[j*3+1]
                 + A_s[j][r*4+2]*Jp_s[j*3+2];
        }
        ar_ws[(size_t)b*192 + i] = val;
    }
}

// ---------------- kernel 3: fused GEMM (v_posed) + LBS epilogue ----------------
// Tile: 64 batches x 192 cols. Fragments direct from global (L2-hot), LDS only
// for C redistribution (64 x 196 f32 = 50 KB). launch_bounds(512,6) -> 3 blocks/CU.
__global__ __launch_bounds__(512, 6) void k_gemm_lbs(const ushort* __restrict__ WA,
                                                     const ushort* __restrict__ WB,
                                                     const float* __restrict__ ar,
                                                     const float* __restrict__ wts,
                                                     float* __restrict__ out)
{
    __shared__ __align__(16) float Cs[64][196];

    // XCD-bijective swizzle: 832 blocks = 8 XCDs x 104; keep same-by blocks on one XCD
    int bid = blockIdx.x;
    int swz = (bid & 7) * 104 + (bid >> 3);
    int bx = swz % 13, by = swz / 13;
    int n0 = bx * 192, b0 = by * 64;

    int tid = threadIdx.x;
    int wv = __builtin_amdgcn_readfirstlane(tid >> 6);   // wave id 0..7
    int lane = tid & 63;
    int wm = wv >> 2;          // 0..1 : 32-batch half
    int wn = wv & 3;           // 0..3 : 48-col quarter
    int l15 = lane & 15, lk = (lane >> 4) * 8;

    const ushort* Abase = WA + (size_t)(b0 + wm*32 + l15)*KPAD + lk;
    const ushort* Bbase = WB + (size_t)(n0 + wn*48 + l15)*KPAD + lk;

    f32x4 acc[2][3] = {};
    #pragma unroll
    for (int ks = 0; ks < 5; ks++) {
        bf16x8 a[2], bf[3];
        #pragma unroll
        for (int mi = 0; mi < 2; mi++)
            a[mi] = *(const bf16x8*)(Abase + (size_t)mi*16*KPAD + ks*32);
        #pragma unroll
        for (int ni = 0; ni < 3; ni++)
            bf[ni] = *(const bf16x8*)(Bbase + (size_t)ni*16*KPAD + ks*32);
        #pragma unroll
        for (int mi = 0; mi < 2; mi++)
            #pragma unroll
            for (int ni = 0; ni < 3; ni++)
                acc[mi][ni] = __builtin_amdgcn_mfma_f32_16x16x32_bf16(a[mi], bf[ni], acc[mi][ni], 0, 0, 0);
    }

    // scatter C tile to LDS (row=batch-local, col=n-local)
    #pragma unroll
    for (int mi = 0; mi < 2; mi++)
        #pragma unroll
        for (int ni = 0; ni < 3; ni++)
            #pragma unroll
            for (int r = 0; r < 4; r++)
                Cs[wm*32 + mi*16 + 4*(lane>>4) + r][wn*48 + ni*16 + l15] = acc[mi][ni][r];
    __syncthreads();

    // LBS epilogue: lane = local vertex, each wave does 8 batches
    int vloc = lane;
    int v = bx*64 + vloc;
    bool vok = (v < NV);
    float w16[16];
    if (vok) {
        #pragma unroll
        for (int j = 0; j < 16; j++) w16[j] = wts[(size_t)v*16 + j];
    } else {
        #pragma unroll
        for (int j = 0; j < 16; j++) w16[j] = 0.f;
    }

    int fp = (v == 320) ? 4 : (v == 443) ? 8 : (v == 672) ? 12
           : (v == 555) ? 16 : (v == 744) ? 20 : -1;

    for (int bi = 0; bi < 8; bi++) {
        int bloc = wv*8 + bi;
        int b = b0 + bloc;
        const float* arb = ar + (size_t)b * 192;   // wave-uniform -> s_load
        float x = Cs[bloc][3*vloc + 0];
        float y = Cs[bloc][3*vloc + 1];
        float z = Cs[bloc][3*vloc + 2];
        float m[12];
        #pragma unroll
        for (int k = 0; k < 12; k++) m[k] = 0.f;
        #pragma unroll
        for (int j = 0; j < 16; j++) {
            float wj = w16[j];
            #pragma unroll
            for (int k = 0; k < 12; k++) m[k] += wj * arb[j*12 + k];
        }
        if (vok) {
            float o0 = m[0]*x + m[1]*y + m[2]*z  + m[3];
            float o1 = m[4]*x + m[5]*y + m[6]*z  + m[7];
            float o2 = m[8]*x + m[9]*y + m[10]*z + m[11];
            size_t base = OUT_JV + (size_t)b*JVROW + (size_t)(21 + v)*3;
            out[base + 0] = o0; out[base + 1] = o1; out[base + 2] = o2;
            if (fp >= 0) {
                size_t jb = OUT_JV + (size_t)b*JVROW + (size_t)fp*3;
                out[jb + 0] = o0; out[jb + 1] = o1; out[jb + 2] = o2;
            }
        }
    }
}

extern "C" void kernel_launch(void* const* d_in, const int* in_sizes, int n_in,
                              void* d_out, int out_size, void* d_ws, size_t ws_size,
                              hipStream_t stream)
{
    const float* rot  = (const float*)d_in[0];
    const float* pp   = (const float*)d_in[1];
    const float* sp   = (const float*)d_in[2];
    const float* vt   = (const float*)d_in[3];
    const float* sd   = (const float*)d_in[4];
    const float* pdir = (const float*)d_in[5];
    const float* jr   = (const float*)d_in[6];
    const float* wts  = (const float*)d_in[7];
    const float* hc   = (const float*)d_in[8];
    const float* hm   = (const float*)d_in[9];
    const int*   faces= (const int*)d_in[10];
    float* out = (float*)d_out;
    float* ws  = (float*)d_ws;

    const ushort* WA = (const ushort*)((char*)d_ws + WA_BYTES);
    const ushort* WB = (const ushort*)((char*)d_ws + WB_BYTES);

    k_prep<<<132 + (NPAD*KPAD + 255)/256, 256, 0, stream>>>(jr, vt, sd, pdir, ws,
                (__hip_bfloat16*)((char*)d_ws + WB_BYTES));
    k_batch<<<NB, 64, 0, stream>>>(rot, pp, sp, hc, hm, faces, ws, out);
    k_gemm_lbs<<<13 * (NB/64), 512, 0, stream>>>(WA, WB, ws + WS_AR, wts, out);
}